// Round 1
// baseline (105.096 us; speedup 1.0000x reference)
//
#include <hip/hip_runtime.h>

typedef short  bf16x8  __attribute__((ext_vector_type(8)));
typedef int    int32x4 __attribute__((ext_vector_type(4)));

#define JS      13           // j-splits (grid.y)
#define STREAMS (JS * 4)     // 52 wave-streams per i-tile (stride in j-tiles)
#define TI      128          // i-points per block (4 MFMA groups per A-load)
#define DEPTH   2            // prefetch depth (buffers X/Y)

__device__ __forceinline__ unsigned short f2bf(float x) {
    unsigned u = __builtin_bit_cast(unsigned, x);
    u += 0x7FFF + ((u >> 16) & 1);          // RNE
    return (unsigned short)(u >> 16);
}
__device__ __forceinline__ float bf2f(unsigned short h) {
    unsigned u = ((unsigned)h) << 16;
    return __builtin_bit_cast(float, u);
}

// ---- pack padding points into MFMA-A planes + zero the output ----
// Row j (K=16 bf16): k0-2 qh | k3-5 ql | k6-8 qh | k9-11 ql | k12-13 negc h/l |
// k14-15 = 1.0,1.0 (pair B's -ha hi/lo threshold fold).
// plane0 = k0-7 (lanes 0-31), plane1 = k8-15 (lanes 32-63).
__global__ __launch_bounds__(256) void dens_pack_kernel(
    const float* __restrict__ pad, uint4* __restrict__ ws,
    int* __restrict__ out, int M, int mtot, int N)
{
    const int j = blockIdx.x * 256 + threadIdx.x;
    if (j < N) out[j] = 0;                      // fold output zeroing here
    if (j >= mtot) return;

    float qx = 0.f, qy = 0.f, qz = 0.f;
    float negc = -1.0e6f;                       // padded rows: s<0 -> sign -1 cancels baseline
    if (j < M) {
        qx = pad[3 * j]; qy = pad[3 * j + 1]; qz = pad[3 * j + 2];
        negc = 0.125f - 0.5f * (qx * qx + qy * qy + qz * qz);   // (r^2 - |q|^2)/2
    }
    const unsigned short xh = f2bf(qx), yh = f2bf(qy), zh = f2bf(qz);
    const unsigned short xl = f2bf(qx - bf2f(xh));
    const unsigned short yl = f2bf(qy - bf2f(yh));
    const unsigned short zl = f2bf(qz - bf2f(zh));
    const unsigned short ch = f2bf(negc);
    const unsigned short cl = f2bf(negc - bf2f(ch));

    uint4 p0, p1;
    p0.x = (unsigned)xh | ((unsigned)yh << 16);   // k0,k1
    p0.y = (unsigned)zh | ((unsigned)xl << 16);   // k2,k3
    p0.z = (unsigned)yl | ((unsigned)zl << 16);   // k4,k5
    p0.w = (unsigned)xh | ((unsigned)yh << 16);   // k6,k7
    p1.x = (unsigned)zh | ((unsigned)xl << 16);   // k8,k9
    p1.y = (unsigned)yl | ((unsigned)zl << 16);   // k10,k11
    p1.z = (unsigned)ch | ((unsigned)cl << 16);   // k12,k13
    p1.w = 0x3F803F80u;                           // k14,k15 = 1.0,1.0
    ws[j]        = p0;                            // plane0
    ws[mtot + j] = p1;                            // plane1
}

// B-frag with threshold folded into k14/k15: s = p.q + negc - ha, within <=> s>=0.
__device__ __forceinline__ void make_bfrag(const float* __restrict__ pc,
                                           int i, int N, int half, bf16x8& B)
{
    float px = 0.f, py = 0.f, pz = 0.f;
    float ha = 3.0e38f;                          // i-pad: s ~ -3e38 < 0 always
    if (i < N) {
        px = pc[3 * i]; py = pc[3 * i + 1]; pz = pc[3 * i + 2];
        ha = 0.5f * (px * px + py * py + pz * pz);   // |p|^2/2, fp32
    }
    const float nha = -ha;
    const unsigned short nhh = f2bf(nha);
    const unsigned short nhl = f2bf(nha - bf2f(nhh));   // 2-term split, err ~1e-5
    const short xh = (short)f2bf(px), yh = (short)f2bf(py), zh = (short)f2bf(pz);
    const short xl = (short)f2bf(px - bf2f((unsigned short)xh));
    const short yl = (short)f2bf(py - bf2f((unsigned short)yh));
    const short zl = (short)f2bf(pz - bf2f((unsigned short)zh));
    const short ONE = (short)0x3F80;
    const bf16x8 Blo = {xh, yh, zh, xh, yh, zh, xl, yl};                    // k0-7
    const bf16x8 Bhi = {zl, xl, yl, zl, ONE, ONE, (short)nhh, (short)nhl};  // k8-15
    B = half ? Bhi : Blo;
}

// sign-extract one D bank in place: 0x00000000 (within, s>=0) / 0xFFFFFFFF (out).
// Reinterpreted as i8 these are 4x{0,-1} per value -> fed to i8 reduction MFMA.
#define SGN_D0 \
    "v_ashrrev_i32 v32, 31, v32\n\t" "v_ashrrev_i32 v33, 31, v33\n\t" \
    "v_ashrrev_i32 v34, 31, v34\n\t" "v_ashrrev_i32 v35, 31, v35\n\t" \
    "v_ashrrev_i32 v36, 31, v36\n\t" "v_ashrrev_i32 v37, 31, v37\n\t" \
    "v_ashrrev_i32 v38, 31, v38\n\t" "v_ashrrev_i32 v39, 31, v39\n\t" \
    "v_ashrrev_i32 v40, 31, v40\n\t" "v_ashrrev_i32 v41, 31, v41\n\t" \
    "v_ashrrev_i32 v42, 31, v42\n\t" "v_ashrrev_i32 v43, 31, v43\n\t" \
    "v_ashrrev_i32 v44, 31, v44\n\t" "v_ashrrev_i32 v45, 31, v45\n\t" \
    "v_ashrrev_i32 v46, 31, v46\n\t" "v_ashrrev_i32 v47, 31, v47\n\t"
#define SGN_D1 \
    "v_ashrrev_i32 v48, 31, v48\n\t" "v_ashrrev_i32 v49, 31, v49\n\t" \
    "v_ashrrev_i32 v50, 31, v50\n\t" "v_ashrrev_i32 v51, 31, v51\n\t" \
    "v_ashrrev_i32 v52, 31, v52\n\t" "v_ashrrev_i32 v53, 31, v53\n\t" \
    "v_ashrrev_i32 v54, 31, v54\n\t" "v_ashrrev_i32 v55, 31, v55\n\t" \
    "v_ashrrev_i32 v56, 31, v56\n\t" "v_ashrrev_i32 v57, 31, v57\n\t" \
    "v_ashrrev_i32 v58, 31, v58\n\t" "v_ashrrev_i32 v59, 31, v59\n\t" \
    "v_ashrrev_i32 v60, 31, v60\n\t" "v_ashrrev_i32 v61, 31, v61\n\t" \
    "v_ashrrev_i32 v62, 31, v62\n\t" "v_ashrrev_i32 v63, 31, v63\n\t"

// i8 reduction: acc[i][col-range g] += sum_k sign_bytes. K=32 spans the 4-reg
// quad of BOTH lane-halves (8 j-rows per MFMA); 4 MFMAs consume a 16-reg bank.
// B (BR) is the per-group column mask: 0x01 bytes only in cols 8g..8g+7, so all
// four i-groups share one 16-reg i32 accumulator (v[96:111], 16-aligned).
// Each indicator is counted x4 (4 bytes) -> /4 in the epilogue.
#define RED_D0(BR) \
    "v_mfma_i32_32x32x32_i8 v[96:111], v[32:35], " BR ", v[96:111]\n\t" \
    "v_mfma_i32_32x32x32_i8 v[96:111], v[36:39], " BR ", v[96:111]\n\t" \
    "v_mfma_i32_32x32x32_i8 v[96:111], v[40:43], " BR ", v[96:111]\n\t" \
    "v_mfma_i32_32x32x32_i8 v[96:111], v[44:47], " BR ", v[96:111]\n\t"
#define RED_D1(BR) \
    "v_mfma_i32_32x32x32_i8 v[96:111], v[48:51], " BR ", v[96:111]\n\t" \
    "v_mfma_i32_32x32x32_i8 v[96:111], v[52:55], " BR ", v[96:111]\n\t" \
    "v_mfma_i32_32x32x32_i8 v[96:111], v[56:59], " BR ", v[96:111]\n\t" \
    "v_mfma_i32_32x32x32_i8 v[96:111], v[60:63], " BR ", v[96:111]\n\t"

// One visit on A-buffer AR: ONE 1KB wave-load feeds FOUR bf16 MFMAs (i-groups
// 0-3). Counting offloaded to the (previously ~4%-utilized) MFMA pipe via i8
// reduction MFMAs; VALU per visit drops 98 -> ~70 instrs. Addr-march fills the
// MFMA->VALU read-hazard gap (replaces the old s_nop 7 / s_nop 2).
// AR reload issued only after the last bf16 MFMA reads it (in-order WAR-safe).
#define VISIT(AR) \
    "s_waitcnt vmcnt(1)\n\t" \
    "v_mfma_f32_32x32x16_bf16 v[32:47], " AR ", %[B0], v[64:79]\n\t" \
    "v_mfma_f32_32x32x16_bf16 v[48:63], " AR ", %[B1], v[64:79]\n\t" \
    "v_add_co_u32 v88, vcc, 0x6800, v88\n\t" \
    "v_addc_co_u32 v89, vcc, 0, v89, vcc\n\t" \
    "s_nop 4\n\t" \
    SGN_D0 \
    RED_D0("%[R0]") \
    "v_mfma_f32_32x32x16_bf16 v[32:47], " AR ", %[B2], v[64:79]\n\t" \
    SGN_D1 \
    RED_D1("%[R1]") \
    "v_mfma_f32_32x32x16_bf16 v[48:63], " AR ", %[B3], v[64:79]\n\t" \
    "global_load_dwordx4 " AR ", v[88:89], off\n\t" \
    SGN_D0 \
    RED_D0("%[R2]") \
    SGN_D1 \
    RED_D1("%[R3]")

// grid (157 x 13), 256 thr. 128-wide i-tile; 52 wave-streams stride j-tiles.
// Physical map: d0=v[32:47] d1=v[48:63] Z=v[64:79] X=v[80:83] Y=v[84:87]
//               addr=v[88:89] (marching, +0x6800/load) acc=v[96:111] (i32).
// 16 visits, 8 iterations.
__global__ __launch_bounds__(256, 4) void dens_mfma_kernel(
    const float* __restrict__ pc,     // [N,3] pointcloud
    const char*  __restrict__ wsA,    // packed A planes ((visits+DEPTH)*STREAMS tiles)
    int* __restrict__ out,            // [N] counts (pre-zeroed)
    int N, int iters, int p1off, int visits)
{
    const int lane = threadIdx.x & 63;
    const int w    = threadIdx.x >> 6;   // wave 0..3
    const int n    = lane & 31;          // output col within 32-tile = i
    const int half = lane >> 5;          // k-chunk 0/1

    const int ibase = blockIdx.x * TI;
    bf16x8 B0, B1, B2, B3;
    make_bfrag(pc, ibase + n,      N, half, B0);
    make_bfrag(pc, ibase + 32 + n, N, half, B1);
    make_bfrag(pc, ibase + 64 + n, N, half, B2);
    make_bfrag(pc, ibase + 96 + n, N, half, B3);

    // per-group column masks for the i8 reduction B operand: lane covers
    // output col (lane&31); group g owns cols 8g..8g+7 of the shared acc.
    const int gsel = n >> 3;
    const int m0 = (gsel == 0) ? 0x01010101 : 0;
    const int m1 = (gsel == 1) ? 0x01010101 : 0;
    const int m2 = (gsel == 2) ? 0x01010101 : 0;
    const int m3 = (gsel == 3) ? 0x01010101 : 0;
    const int32x4 R0 = {m0, m0, m0, m0};
    const int32x4 R1 = {m1, m1, m1, m1};
    const int32x4 R2 = {m2, m2, m2, m2};
    const int32x4 R3 = {m3, m3, m3, m3};

    const int stream = blockIdx.y * 4 + w;          // 0..51
    const unsigned long long ax =
        (unsigned long long)(wsA + (half ? p1off : 0) + n * 16 + (size_t)stream * 512);
    const unsigned xlo = (unsigned)ax, xhi = (unsigned)(ax >> 32);

    int it = iters;
    int a0, a1, a2, a3, a4, a5, a6, a7, a8, a9, a10, a11, a12, a13, a14, a15;

    asm volatile(
        // ---- preamble: marching addr, Z=0 bank, acc=0, DEPTH prefetches ----
        // (addr-inc now precedes each load in VISIT, so only ONE inc here)
        "v_mov_b32 v88, %[xlo]\n\t"
        "v_mov_b32 v89, %[xhi]\n\t"
        "v_mov_b32 v64, 0\n\t" "v_mov_b32 v65, 0\n\t"
        "v_mov_b32 v66, 0\n\t" "v_mov_b32 v67, 0\n\t"
        "v_mov_b32 v68, 0\n\t" "v_mov_b32 v69, 0\n\t"
        "v_mov_b32 v70, 0\n\t" "v_mov_b32 v71, 0\n\t"
        "v_mov_b32 v72, 0\n\t" "v_mov_b32 v73, 0\n\t"
        "v_mov_b32 v74, 0\n\t" "v_mov_b32 v75, 0\n\t"
        "v_mov_b32 v76, 0\n\t" "v_mov_b32 v77, 0\n\t"
        "v_mov_b32 v78, 0\n\t" "v_mov_b32 v79, 0\n\t"
        "v_mov_b32 v96, 0\n\t"  "v_mov_b32 v97, 0\n\t"
        "v_mov_b32 v98, 0\n\t"  "v_mov_b32 v99, 0\n\t"
        "v_mov_b32 v100, 0\n\t" "v_mov_b32 v101, 0\n\t"
        "v_mov_b32 v102, 0\n\t" "v_mov_b32 v103, 0\n\t"
        "v_mov_b32 v104, 0\n\t" "v_mov_b32 v105, 0\n\t"
        "v_mov_b32 v106, 0\n\t" "v_mov_b32 v107, 0\n\t"
        "v_mov_b32 v108, 0\n\t" "v_mov_b32 v109, 0\n\t"
        "v_mov_b32 v110, 0\n\t" "v_mov_b32 v111, 0\n\t"
        "global_load_dwordx4 v[80:83], v[88:89], off\n\t"
        "v_add_co_u32 v88, vcc, 0x6800, v88\n\t"
        "v_addc_co_u32 v89, vcc, 0, v89, vcc\n\t"
        "global_load_dwordx4 v[84:87], v[88:89], off\n\t"
        "Ldens%=:\n\t"
        VISIT("v[80:83]")
        VISIT("v[84:87]")
        "s_sub_u32 %[it], %[it], 1\n\t"
        "s_cmp_lg_u32 %[it], 0\n\t"
        "s_cbranch_scc1 Ldens%=\n\t"
        // drain MFMA pipe before VALU reads acc (MFMA->VALU read hazard)
        "s_nop 7\n\t" "s_nop 7\n\t" "s_nop 7\n\t"
        "v_mov_b32 %[a0],  v96\n\t"  "v_mov_b32 %[a1],  v97\n\t"
        "v_mov_b32 %[a2],  v98\n\t"  "v_mov_b32 %[a3],  v99\n\t"
        "v_mov_b32 %[a4],  v100\n\t" "v_mov_b32 %[a5],  v101\n\t"
        "v_mov_b32 %[a6],  v102\n\t" "v_mov_b32 %[a7],  v103\n\t"
        "v_mov_b32 %[a8],  v104\n\t" "v_mov_b32 %[a9],  v105\n\t"
        "v_mov_b32 %[a10], v106\n\t" "v_mov_b32 %[a11], v107\n\t"
        "v_mov_b32 %[a12], v108\n\t" "v_mov_b32 %[a13], v109\n\t"
        "v_mov_b32 %[a14], v110\n\t" "v_mov_b32 %[a15], v111\n\t"
        : [a0]"=v"(a0),   [a1]"=v"(a1),   [a2]"=v"(a2),   [a3]"=v"(a3),
          [a4]"=v"(a4),   [a5]"=v"(a5),   [a6]"=v"(a6),   [a7]"=v"(a7),
          [a8]"=v"(a8),   [a9]"=v"(a9),   [a10]"=v"(a10), [a11]"=v"(a11),
          [a12]"=v"(a12), [a13]"=v"(a13), [a14]"=v"(a14), [a15]"=v"(a15),
          [it]"+s"(it)
        : [B0]"v"(B0), [B1]"v"(B1), [B2]"v"(B2), [B3]"v"(B3),
          [R0]"v"(R0), [R1]"v"(R1), [R2]"v"(R2), [R3]"v"(R3),
          [xlo]"v"(xlo), [xhi]"v"(xhi)
        : "vcc", "scc", "memory",
          "v32","v33","v34","v35","v36","v37","v38","v39",
          "v40","v41","v42","v43","v44","v45","v46","v47",
          "v48","v49","v50","v51","v52","v53","v54","v55",
          "v56","v57","v58","v59","v60","v61","v62","v63",
          "v64","v65","v66","v67","v68","v69","v70","v71",
          "v72","v73","v74","v75","v76","v77","v78","v79",
          "v80","v81","v82","v83","v84","v85","v86","v87",
          "v88","v89",
          "v96","v97","v98","v99","v100","v101","v102","v103",
          "v104","v105","v106","v107","v108","v109","v110","v111");

    // acc D-layout (32x32 i32): col = lane&31 (group g = col>>3, value
    // replicated across the 8 cols of its range), row = (q&3)+8*(q>>2)+4*half.
    // acc = -4 * (#not-within) summed over this wave's 32*visits j's
    // -> per-i count for this wave = 32*visits + (acc >> 2).
    const int base = 32 * visits;
    __shared__ int red[4][TI];
    if ((lane & 7) == 0) {                       // one writer per (group,half)
        const int g   = n >> 3;
        const int hi4 = half << 2;               // +4 rows for upper lane-half
        int* rw = &red[w][32 * g];
        rw[ 0 + hi4] = base + (a0  >> 2);
        rw[ 1 + hi4] = base + (a1  >> 2);
        rw[ 2 + hi4] = base + (a2  >> 2);
        rw[ 3 + hi4] = base + (a3  >> 2);
        rw[ 8 + hi4] = base + (a4  >> 2);
        rw[ 9 + hi4] = base + (a5  >> 2);
        rw[10 + hi4] = base + (a6  >> 2);
        rw[11 + hi4] = base + (a7  >> 2);
        rw[16 + hi4] = base + (a8  >> 2);
        rw[17 + hi4] = base + (a9  >> 2);
        rw[18 + hi4] = base + (a10 >> 2);
        rw[19 + hi4] = base + (a11 >> 2);
        rw[24 + hi4] = base + (a12 >> 2);
        rw[25 + hi4] = base + (a13 >> 2);
        rw[26 + hi4] = base + (a14 >> 2);
        rw[27 + hi4] = base + (a15 >> 2);
    }
    __syncthreads();
    if (threadIdx.x < TI) {
        const int ii = ibase + threadIdx.x;
        if (ii < N) {
            const int s = red[0][threadIdx.x] + red[1][threadIdx.x] +
                          red[2][threadIdx.x] + red[3][threadIdx.x];
            atomicAdd(&out[ii], s);
        }
    }
}

extern "C" void kernel_launch(void* const* d_in, const int* in_sizes, int n_in,
                              void* d_out, int out_size, void* d_ws, size_t ws_size,
                              hipStream_t stream) {
    const float* pc  = (const float*)d_in[0];   // [N,3] pointcloud
    const float* pad = (const float*)d_in[1];   // [M,3] pointcloud_padding
    int* out = (int*)d_out;

    const int N = in_sizes[0] / 3;              // 20000
    const int M = in_sizes[1] / 3;              // 25000
    const int jt = (M + 31) / 32;               // 782 j-tiles
    int visits = (jt + STREAMS - 1) / STREAMS;  // 16
    if (visits & 1) visits++;                   // 2-visit unrolled body
    const int jtp  = (visits + DEPTH) * STREAMS;    // 936 tiles incl. prefetch overrun
    const int mtot = jtp * 32;                  // 29952 rows (~958 KB in ws)

    dens_pack_kernel<<<(mtot + 255) / 256, 256, 0, stream>>>(
        pad, (uint4*)d_ws, out, M, mtot, N);

    dim3 grid((N + TI - 1) / TI, JS);           // 157 x 13
    dens_mfma_kernel<<<grid, 256, 0, stream>>>(
        pc, (const char*)d_ws, out, N, visits / 2, mtot * 16, visits);
}

// Round 2
// 90.023 us; speedup vs baseline: 1.1674x; 1.1674x over previous
//
#include <hip/hip_runtime.h>

typedef short  bf16x8  __attribute__((ext_vector_type(8)));
typedef int    int32x4 __attribute__((ext_vector_type(4)));

#define JS      13           // j-splits (grid.y)
#define STREAMS (JS * 4)     // 52 wave-streams per i-tile (stride in j-tiles)
#define TI      128          // i-points per block (4 MFMA groups per A-load)
#define DEPTH   2            // prefetch depth (buffers X/Y)

__device__ __forceinline__ unsigned short f2bf(float x) {
    unsigned u = __builtin_bit_cast(unsigned, x);
    u += 0x7FFF + ((u >> 16) & 1);          // RNE
    return (unsigned short)(u >> 16);
}
__device__ __forceinline__ float bf2f(unsigned short h) {
    unsigned u = ((unsigned)h) << 16;
    return __builtin_bit_cast(float, u);
}

// ---- pack padding points into MFMA-A planes + zero the output ----
// Row j (K=16 bf16): k0-2 qh | k3-5 ql | k6-8 qh | k9-11 ql | k12-13 negc h/l |
// k14-15 = 1.0,1.0 (pair B's -ha hi/lo threshold fold).
// plane0 = k0-7 (lanes 0-31), plane1 = k8-15 (lanes 32-63).
__global__ __launch_bounds__(256) void dens_pack_kernel(
    const float* __restrict__ pad, uint4* __restrict__ ws,
    int* __restrict__ out, int M, int mtot, int N)
{
    const int j = blockIdx.x * 256 + threadIdx.x;
    if (j < N) out[j] = 0;                      // fold output zeroing here
    if (j >= mtot) return;

    float qx = 0.f, qy = 0.f, qz = 0.f;
    float negc = -1.0e6f;                       // padded rows: s<0 -> sign -1 cancels baseline
    if (j < M) {
        qx = pad[3 * j]; qy = pad[3 * j + 1]; qz = pad[3 * j + 2];
        negc = 0.125f - 0.5f * (qx * qx + qy * qy + qz * qz);   // (r^2 - |q|^2)/2
    }
    const unsigned short xh = f2bf(qx), yh = f2bf(qy), zh = f2bf(qz);
    const unsigned short xl = f2bf(qx - bf2f(xh));
    const unsigned short yl = f2bf(qy - bf2f(yh));
    const unsigned short zl = f2bf(qz - bf2f(zh));
    const unsigned short ch = f2bf(negc);
    const unsigned short cl = f2bf(negc - bf2f(ch));

    uint4 p0, p1;
    p0.x = (unsigned)xh | ((unsigned)yh << 16);   // k0,k1
    p0.y = (unsigned)zh | ((unsigned)xl << 16);   // k2,k3
    p0.z = (unsigned)yl | ((unsigned)zl << 16);   // k4,k5
    p0.w = (unsigned)xh | ((unsigned)yh << 16);   // k6,k7
    p1.x = (unsigned)zh | ((unsigned)xl << 16);   // k8,k9
    p1.y = (unsigned)yl | ((unsigned)zl << 16);   // k10,k11
    p1.z = (unsigned)ch | ((unsigned)cl << 16);   // k12,k13
    p1.w = 0x3F803F80u;                           // k14,k15 = 1.0,1.0
    ws[j]        = p0;                            // plane0
    ws[mtot + j] = p1;                            // plane1
}

// B-frag with threshold folded into k14/k15: s = p.q + negc - ha, within <=> s>=0.
__device__ __forceinline__ void make_bfrag(const float* __restrict__ pc,
                                           int i, int N, int half, bf16x8& B)
{
    float px = 0.f, py = 0.f, pz = 0.f;
    float ha = 3.0e38f;                          // i-pad: s ~ -3e38 < 0 always
    if (i < N) {
        px = pc[3 * i]; py = pc[3 * i + 1]; pz = pc[3 * i + 2];
        ha = 0.5f * (px * px + py * py + pz * pz);   // |p|^2/2, fp32
    }
    const float nha = -ha;
    const unsigned short nhh = f2bf(nha);
    const unsigned short nhl = f2bf(nha - bf2f(nhh));   // 2-term split, err ~1e-5
    const short xh = (short)f2bf(px), yh = (short)f2bf(py), zh = (short)f2bf(pz);
    const short xl = (short)f2bf(px - bf2f((unsigned short)xh));
    const short yl = (short)f2bf(py - bf2f((unsigned short)yh));
    const short zl = (short)f2bf(pz - bf2f((unsigned short)zh));
    const short ONE = (short)0x3F80;
    const bf16x8 Blo = {xh, yh, zh, xh, yh, zh, xl, yl};                    // k0-7
    const bf16x8 Bhi = {zl, xl, yl, zl, ONE, ONE, (short)nhh, (short)nhl};  // k8-15
    B = half ? Bhi : Blo;
}

// ---- packed sign-byte gather: 4 f32 D regs -> 1 reg of 4 bytes {0x80|0x00} ----
// v_perm_b32 byte selectors (standard): 0-3 = S1.byte[sel], 4-7 = S0.byte[sel-4],
// 0x0C = 0x00. byte3 of an f32 = sign|exp[7:1]; AND 0x80 isolates the sign.
// SEL_LO = 0x0C0C0703: {b0: S1.b3, b1: S0.b3, 0, 0}
// SEL_HI = 0x07030C0C: {0, 0, b2: S1.b3, b3: S0.b3}
// Byte order within the packed reg is irrelevant (everything is summed).
#define PACK4(D, S0, S1, S2, S3, T) \
    "v_perm_b32 " D ", " S0 ", " S1 ", %[SL]\n\t" \
    "v_perm_b32 " T ", " S2 ", " S3 ", %[SH]\n\t" \
    "v_or_b32 "  D ", " D ", " T "\n\t" \
    "v_and_b32 " D ", 0x80808080, " D "\n\t"

// bank d0 = v[32:47] -> P = v[92:95] (scratch v90)
#define PACK_D0 \
    PACK4("v92", "v32", "v33", "v34", "v35", "v90") \
    PACK4("v93", "v36", "v37", "v38", "v39", "v90") \
    PACK4("v94", "v40", "v41", "v42", "v43", "v90") \
    PACK4("v95", "v44", "v45", "v46", "v47", "v90")
// bank d1 = v[48:63] -> Q = v[112:115] (scratch v91)
#define PACK_D1 \
    PACK4("v112", "v48", "v49", "v50", "v51", "v91") \
    PACK4("v113", "v52", "v53", "v54", "v55", "v91") \
    PACK4("v114", "v56", "v57", "v58", "v59", "v91") \
    PACK4("v115", "v60", "v61", "v62", "v63", "v91")

// ONE i8 MFMA reduces a whole bank: A row r = lane&31 = local i; lane-halves
// supply k=0..15 / 16..31 -> all 32 j-indicators of the bank summed per i.
// A bytes are -128 (miss) / 0 (within); B mask 0x01 only in group-g's 8 cols
// -> four i-groups share one 16-reg i32 acc. acc = -128 * miss.
#define RED(PR, BR) \
    "v_mfma_i32_32x32x32_i8 v[96:111], " PR ", " BR ", v[96:111]\n\t"

// One visit on A-buffer AR: ONE 1KB wave-load feeds FOUR bf16 MFMAs (i-groups
// 0-3). Per bank: 16 pack VALU + 1 i8 MFMA (vs r1's 16 ashr + 4 MFMA; vs r0's
// 16 ashr + 8 add3). Per visit: 66 VALU + 8 MFMA. All MFMA->VALU reads have
// >=19cy cover (r0's proven margin); all pack->i8 reads have >=8cy cover.
// AR reload issued only after the last bf16 MFMA reads it (in-order WAR-safe).
#define VISIT(AR) \
    "s_waitcnt vmcnt(1)\n\t" \
    "v_mfma_f32_32x32x16_bf16 v[32:47], " AR ", %[B0], v[64:79]\n\t" \
    "v_mfma_f32_32x32x16_bf16 v[48:63], " AR ", %[B1], v[64:79]\n\t" \
    "v_add_co_u32 v88, vcc, 0x6800, v88\n\t" \
    "v_addc_co_u32 v89, vcc, 0, v89, vcc\n\t" \
    "s_nop 6\n\t" \
    PACK_D0 \
    "v_mfma_f32_32x32x16_bf16 v[32:47], " AR ", %[B2], v[64:79]\n\t" \
    RED("v[92:95]", "%[R0]") \
    PACK_D1 \
    "v_mfma_f32_32x32x16_bf16 v[48:63], " AR ", %[B3], v[64:79]\n\t" \
    RED("v[112:115]", "%[R1]") \
    "global_load_dwordx4 " AR ", v[88:89], off\n\t" \
    PACK_D0 \
    PACK_D1 \
    RED("v[92:95]", "%[R2]") \
    RED("v[112:115]", "%[R3]")

// grid (157 x 13), 256 thr. 128-wide i-tile; 52 wave-streams stride j-tiles.
// Physical map: d0=v[32:47] d1=v[48:63] Z=v[64:79] X=v[80:83] Y=v[84:87]
//               addr=v[88:89] scratch=v90/91 P=v[92:95] acc=v[96:111]
//               Q=v[112:115]. 16 visits, 8 iterations.
__global__ __launch_bounds__(256, 4) void dens_mfma_kernel(
    const float* __restrict__ pc,     // [N,3] pointcloud
    const char*  __restrict__ wsA,    // packed A planes ((visits+DEPTH)*STREAMS tiles)
    int* __restrict__ out,            // [N] counts (pre-zeroed)
    int N, int iters, int p1off, int visits)
{
    const int lane = threadIdx.x & 63;
    const int w    = threadIdx.x >> 6;   // wave 0..3
    const int n    = lane & 31;          // output col within 32-tile = i
    const int half = lane >> 5;          // k-chunk 0/1

    const int ibase = blockIdx.x * TI;
    bf16x8 B0, B1, B2, B3;
    make_bfrag(pc, ibase + n,      N, half, B0);
    make_bfrag(pc, ibase + 32 + n, N, half, B1);
    make_bfrag(pc, ibase + 64 + n, N, half, B2);
    make_bfrag(pc, ibase + 96 + n, N, half, B3);

    // per-group column masks for the i8 reduction B operand: lane covers
    // output col (lane&31); group g owns cols 8g..8g+7 of the shared acc.
    const int gsel = n >> 3;
    const int m0 = (gsel == 0) ? 0x01010101 : 0;
    const int m1 = (gsel == 1) ? 0x01010101 : 0;
    const int m2 = (gsel == 2) ? 0x01010101 : 0;
    const int m3 = (gsel == 3) ? 0x01010101 : 0;
    const int32x4 R0 = {m0, m0, m0, m0};
    const int32x4 R1 = {m1, m1, m1, m1};
    const int32x4 R2 = {m2, m2, m2, m2};
    const int32x4 R3 = {m3, m3, m3, m3};

    const int stream = blockIdx.y * 4 + w;          // 0..51
    const unsigned long long ax =
        (unsigned long long)(wsA + (half ? p1off : 0) + n * 16 + (size_t)stream * 512);
    const unsigned xlo = (unsigned)ax, xhi = (unsigned)(ax >> 32);

    int it = iters;
    int a0, a1, a2, a3, a4, a5, a6, a7, a8, a9, a10, a11, a12, a13, a14, a15;

    asm volatile(
        // ---- preamble: marching addr, Z=0 bank, acc=0, DEPTH prefetches ----
        "v_mov_b32 v88, %[xlo]\n\t"
        "v_mov_b32 v89, %[xhi]\n\t"
        "v_mov_b32 v64, 0\n\t" "v_mov_b32 v65, 0\n\t"
        "v_mov_b32 v66, 0\n\t" "v_mov_b32 v67, 0\n\t"
        "v_mov_b32 v68, 0\n\t" "v_mov_b32 v69, 0\n\t"
        "v_mov_b32 v70, 0\n\t" "v_mov_b32 v71, 0\n\t"
        "v_mov_b32 v72, 0\n\t" "v_mov_b32 v73, 0\n\t"
        "v_mov_b32 v74, 0\n\t" "v_mov_b32 v75, 0\n\t"
        "v_mov_b32 v76, 0\n\t" "v_mov_b32 v77, 0\n\t"
        "v_mov_b32 v78, 0\n\t" "v_mov_b32 v79, 0\n\t"
        "v_mov_b32 v96, 0\n\t"  "v_mov_b32 v97, 0\n\t"
        "v_mov_b32 v98, 0\n\t"  "v_mov_b32 v99, 0\n\t"
        "v_mov_b32 v100, 0\n\t" "v_mov_b32 v101, 0\n\t"
        "v_mov_b32 v102, 0\n\t" "v_mov_b32 v103, 0\n\t"
        "v_mov_b32 v104, 0\n\t" "v_mov_b32 v105, 0\n\t"
        "v_mov_b32 v106, 0\n\t" "v_mov_b32 v107, 0\n\t"
        "v_mov_b32 v108, 0\n\t" "v_mov_b32 v109, 0\n\t"
        "v_mov_b32 v110, 0\n\t" "v_mov_b32 v111, 0\n\t"
        "global_load_dwordx4 v[80:83], v[88:89], off\n\t"
        "v_add_co_u32 v88, vcc, 0x6800, v88\n\t"
        "v_addc_co_u32 v89, vcc, 0, v89, vcc\n\t"
        "global_load_dwordx4 v[84:87], v[88:89], off\n\t"
        "Ldens%=:\n\t"
        VISIT("v[80:83]")
        VISIT("v[84:87]")
        "s_sub_u32 %[it], %[it], 1\n\t"
        "s_cmp_lg_u32 %[it], 0\n\t"
        "s_cbranch_scc1 Ldens%=\n\t"
        // drain MFMA pipe before VALU reads acc (MFMA->VALU read hazard)
        "s_nop 7\n\t" "s_nop 7\n\t" "s_nop 7\n\t"
        "v_mov_b32 %[a0],  v96\n\t"  "v_mov_b32 %[a1],  v97\n\t"
        "v_mov_b32 %[a2],  v98\n\t"  "v_mov_b32 %[a3],  v99\n\t"
        "v_mov_b32 %[a4],  v100\n\t" "v_mov_b32 %[a5],  v101\n\t"
        "v_mov_b32 %[a6],  v102\n\t" "v_mov_b32 %[a7],  v103\n\t"
        "v_mov_b32 %[a8],  v104\n\t" "v_mov_b32 %[a9],  v105\n\t"
        "v_mov_b32 %[a10], v106\n\t" "v_mov_b32 %[a11], v107\n\t"
        "v_mov_b32 %[a12], v108\n\t" "v_mov_b32 %[a13], v109\n\t"
        "v_mov_b32 %[a14], v110\n\t" "v_mov_b32 %[a15], v111\n\t"
        : [a0]"=v"(a0),   [a1]"=v"(a1),   [a2]"=v"(a2),   [a3]"=v"(a3),
          [a4]"=v"(a4),   [a5]"=v"(a5),   [a6]"=v"(a6),   [a7]"=v"(a7),
          [a8]"=v"(a8),   [a9]"=v"(a9),   [a10]"=v"(a10), [a11]"=v"(a11),
          [a12]"=v"(a12), [a13]"=v"(a13), [a14]"=v"(a14), [a15]"=v"(a15),
          [it]"+s"(it)
        : [B0]"v"(B0), [B1]"v"(B1), [B2]"v"(B2), [B3]"v"(B3),
          [R0]"v"(R0), [R1]"v"(R1), [R2]"v"(R2), [R3]"v"(R3),
          [SL]"s"(0x0C0C0703u), [SH]"s"(0x07030C0Cu),
          [xlo]"v"(xlo), [xhi]"v"(xhi)
        : "vcc", "scc", "memory",
          "v32","v33","v34","v35","v36","v37","v38","v39",
          "v40","v41","v42","v43","v44","v45","v46","v47",
          "v48","v49","v50","v51","v52","v53","v54","v55",
          "v56","v57","v58","v59","v60","v61","v62","v63",
          "v64","v65","v66","v67","v68","v69","v70","v71",
          "v72","v73","v74","v75","v76","v77","v78","v79",
          "v80","v81","v82","v83","v84","v85","v86","v87",
          "v88","v89","v90","v91","v92","v93","v94","v95",
          "v96","v97","v98","v99","v100","v101","v102","v103",
          "v104","v105","v106","v107","v108","v109","v110","v111",
          "v112","v113","v114","v115");

    // acc D-layout (32x32 i32): col = lane&31 (group g = col>>3, value
    // replicated across the 8 cols of its range), row = (q&3)+8*(q>>2)+4*half
    // = local i. acc = -128 * (#not-within) over this wave's 32*visits j's
    // -> per-i count for this wave = 32*visits + (acc >> 7).
    const int base = 32 * visits;
    __shared__ int red[4][TI];
    if ((lane & 7) == 0) {                       // one writer per (group,half)
        const int g   = n >> 3;
        const int hi4 = half << 2;               // +4 rows for upper lane-half
        int* rw = &red[w][32 * g];
        rw[ 0 + hi4] = base + (a0  >> 7);
        rw[ 1 + hi4] = base + (a1  >> 7);
        rw[ 2 + hi4] = base + (a2  >> 7);
        rw[ 3 + hi4] = base + (a3  >> 7);
        rw[ 8 + hi4] = base + (a4  >> 7);
        rw[ 9 + hi4] = base + (a5  >> 7);
        rw[10 + hi4] = base + (a6  >> 7);
        rw[11 + hi4] = base + (a7  >> 7);
        rw[16 + hi4] = base + (a8  >> 7);
        rw[17 + hi4] = base + (a9  >> 7);
        rw[18 + hi4] = base + (a10 >> 7);
        rw[19 + hi4] = base + (a11 >> 7);
        rw[24 + hi4] = base + (a12 >> 7);
        rw[25 + hi4] = base + (a13 >> 7);
        rw[26 + hi4] = base + (a14 >> 7);
        rw[27 + hi4] = base + (a15 >> 7);
    }
    __syncthreads();
    if (threadIdx.x < TI) {
        const int ii = ibase + threadIdx.x;
        if (ii < N) {
            const int s = red[0][threadIdx.x] + red[1][threadIdx.x] +
                          red[2][threadIdx.x] + red[3][threadIdx.x];
            atomicAdd(&out[ii], s);
        }
    }
}

extern "C" void kernel_launch(void* const* d_in, const int* in_sizes, int n_in,
                              void* d_out, int out_size, void* d_ws, size_t ws_size,
                              hipStream_t stream) {
    const float* pc  = (const float*)d_in[0];   // [N,3] pointcloud
    const float* pad = (const float*)d_in[1];   // [M,3] pointcloud_padding
    int* out = (int*)d_out;

    const int N = in_sizes[0] / 3;              // 20000
    const int M = in_sizes[1] / 3;              // 25000
    const int jt = (M + 31) / 32;               // 782 j-tiles
    int visits = (jt + STREAMS - 1) / STREAMS;  // 16
    if (visits & 1) visits++;                   // 2-visit unrolled body
    const int jtp  = (visits + DEPTH) * STREAMS;    // 936 tiles incl. prefetch overrun
    const int mtot = jtp * 32;                  // 29952 rows (~958 KB in ws)

    dens_pack_kernel<<<(mtot + 255) / 256, 256, 0, stream>>>(
        pad, (uint4*)d_ws, out, M, mtot, N);

    dim3 grid((N + TI - 1) / TI, JS);           // 157 x 13
    dens_mfma_kernel<<<grid, 256, 0, stream>>>(
        pc, (const char*)d_ws, out, N, visits / 2, mtot * 16, visits);
}